// Round 1
// baseline (1521.114 us; speedup 1.0000x reference)
//
#include <hip/hip_runtime.h>
#include <cstdint>
#include <cstddef>

// BloomAttention MI355X implementation.
// Round 3: GEMMs rewritten to the 256x256 8-phase schedule (HK-derived template):
//   - BM=BN=256, BK=64, 8 waves (2Mx4N), 512 threads, 128 KiB LDS
//   - double-buffered K-tiles (even->buf0, odd->buf1), staged as 4 half-tiles
//     (A0,A1,B0,B1 of 128x64) via global_load_lds x16B, 1 half-tile per phase
//   - counted s_waitcnt vmcnt(6) ONLY at phases 4 and 8 (3 half-tiles in flight),
//     raw s_barrier (no full drain), s_setprio(1) around each 16-MFMA quadrant
//   - LDS XOR-swizzle (slot ^= row&7, 16B slots) applied as inverse-swizzled
//     GLOBAL source + linear LDS dest + swizzled ds_read (both-sides rule)
//   - XCD-aware block swizzle (grid % 8 == 0 for both GEMMs)
// Overwrite/residency ledger (per iter, K-tiles 2i->buf0, 2i+1->buf1):
//   reads: P0: A0-3+B0-3(buf0) P2: A4-7(buf0) P4: A0-3+B0-3(buf1) P6: A4-7(buf1)
//   stages: P0:Kt2i+1.A1  P1:Kt2i+2.B0  P2:Kt2i+2.B1  P3:Kt2i+2.A0 [vmcnt6]
//           P4:Kt2i+2.A1  P5:Kt2i+3.B0  P6:Kt2i+3.B1  P7:Kt2i+3.A0 [vmcnt6]
//   every stage lands in a slot whose last ds_read was >=1 phase earlier;
//   vmcnt(6) at P3 covers Kt2i+1, at P7 covers Kt2i+2. Tail prefetches past K
//   read mapped workspace garbage that is never consumed (uniform vmcnt counts).
// flash_attn / transposes unchanged from round 2.
//
// Workspace layout (256 MB, liveness overlap):
//   [0,32M)    A_bf16   (later reused as ctx)
//   [32,128M)  W1T      (later reused as W2T)
//   [128,224M) fused
//   [224,256M) VT

typedef unsigned short u16;
typedef unsigned int u32;
typedef __bf16 bf16x8 __attribute__((ext_vector_type(8)));
typedef float f32x4 __attribute__((ext_vector_type(4)));
typedef u16 u16x4 __attribute__((ext_vector_type(4)));

#define LDS_AS(p) ((__attribute__((address_space(3))) u32*)(p))
#define GLB_AS(p) ((__attribute__((address_space(1))) u32*)(p))

// async global->LDS, 16B per lane; LDS dest = wave-uniform base + lane*16,
// global source is PER-LANE (this is what makes the XOR swizzle possible).
__device__ __forceinline__ void load16(const void* g, void* l) {
  __builtin_amdgcn_global_load_lds(GLB_AS(g), LDS_AS(l), 16, 0, 0);
}

__device__ __forceinline__ u16 f2bf(float f) {
  union { float f; u32 u; } x; x.f = f;
  u32 r = x.u + 0x7fffu + ((x.u >> 16) & 1u);  // RNE
  return (u16)(r >> 16);
}

// ---------------- elementwise f32 -> bf16 ----------------
__global__ __launch_bounds__(256) void cvt_bf16(const float* __restrict__ in,
                                                u16* __restrict__ out, int n) {
  int i = (blockIdx.x * 256 + threadIdx.x) * 4;
  if (i >= n) return;
  float4 v = *(const float4*)(in + i);
  u16x4 o = { f2bf(v.x), f2bf(v.y), f2bf(v.z), f2bf(v.w) };
  *(u16x4*)(out + i) = o;
}

// ---------------- f32 [K][N] -> bf16 [N][K] (transpose+convert) ----------------
__global__ __launch_bounds__(256) void cvt_transpose(const float* __restrict__ W,
                                                     u16* __restrict__ WT,
                                                     int K, int N) {
  __shared__ float tile[32][33];
  int n0 = blockIdx.x * 32, k0 = blockIdx.y * 32;
  int tx = threadIdx.x & 31, ty = threadIdx.x >> 5;  // 32 x 8
  for (int r = ty; r < 32; r += 8)
    tile[r][tx] = W[(size_t)(k0 + r) * N + n0 + tx];
  __syncthreads();
  for (int r = ty; r < 32; r += 8)
    WT[(size_t)(n0 + r) * K + k0 + tx] = f2bf(tile[tx][r]);
}

// ---------------- V slice of fused -> VT[B*H][HD][S] ----------------
__global__ __launch_bounds__(256) void transpose_v(const u16* __restrict__ fused,
                                                   u16* __restrict__ vt) {
  __shared__ __align__(16) u16 tile[64][136];
  int st = blockIdx.x * 64, bh = blockIdx.y;
  int b = bh >> 5, h = bh & 31;
  int tx = threadIdx.x & 15, ty = threadIdx.x >> 4;  // 16 x 16
  for (int r = ty; r < 64; r += 16) {
    const u16* src = fused + (size_t)(b * 2048 + st + r) * 12288 + h * 384 + 256 + tx * 8;
    u16x4 a = *(const u16x4*)(src);
    u16x4 c = *(const u16x4*)(src + 4);
    *(u16x4*)&tile[r][tx * 8] = a;
    *(u16x4*)&tile[r][tx * 8 + 4] = c;
  }
  __syncthreads();
  for (int d = ty; d < 128; d += 16) {
    u16x4 o = { tile[tx * 4 + 0][d], tile[tx * 4 + 1][d],
                tile[tx * 4 + 2][d], tile[tx * 4 + 3][d] };
    *(u16x4*)(vt + ((size_t)bh * 128 + d) * 2048 + st + tx * 4) = o;
  }
}

// ---------------- 256x256 8-phase bf16 GEMM: C = A[M,K] * BT[N,K]^T + bias (+res) ----
// EPI 0: out bf16.  EPI 1: out f32 with +residual.
// Requires: M%256==0, N%256==0, K%128==0, grid 1-D with nwg%8==0.
template <int EPI>
__global__ __launch_bounds__(512, 2) void gemm256(const u16* __restrict__ A,
                                                  const u16* __restrict__ BT,
                                                  const float* __restrict__ bias,
                                                  const float* __restrict__ res,
                                                  void* __restrict__ out,
                                                  int M, int N, int K) {
  // [buf][half: A0,A1,B0,B1][128 rows x 64 cols bf16] = 128 KiB
  __shared__ __align__(16) u16 lds[2][4][8192];
  char* ldsB = (char*)lds;

  const int tid = threadIdx.x, wave = tid >> 6, lane = tid & 63;
  const int quad = lane >> 4, l16 = lane & 15;
  const int wr = wave >> 2, wc = wave & 3;  // 2 x 4 wave grid

  // XCD-aware swizzle (bijective since nwg % 8 == 0)
  const int nwg = gridDim.x, per = nwg >> 3, bid = blockIdx.x;
  const int swz = (bid & 7) * per + (bid >> 3);
  const int ntn = N >> 8;
  const int tm = swz / ntn, tn = swz - tm * ntn;
  const int m0 = tm << 8, n0 = tn << 8;

  // ---- staging geometry: half-tile = 128x64 bf16 = 16 KB = 2 insts x 8 KB.
  // inst j covers LDS bytes [j*8192 +wave*1024 +lane*16); row = j*64+wave*8+lane>>3,
  // 16B slot = lane&7. Source slot = lds_slot ^ (row&7)  (inverse XOR swizzle).
  const int r0 = wave * 8 + (lane >> 3);
  const int scb = ((lane & 7) ^ ((lane >> 3) & 7)) << 4;
  const char* Ab = (const char*)A;
  const char* Bb = (const char*)BT;
  const size_t ROW64 = (size_t)K * 128;  // 64 rows of bf16 [*][K]
  size_t aOff[2], bOff[2];
#pragma unroll
  for (int h = 0; h < 2; ++h) {
    aOff[h] = ((size_t)(m0 + h * 128 + r0) * K) * 2 + scb;
    bOff[h] = ((size_t)(n0 + h * 128 + r0) * K) * 2 + scb;
  }

#define STAGE_A(b, h, kt) do {                                                  \
    char* d_ = ldsB + (((b) * 4 + (h)) * 16384) + wave * 1024;                  \
    load16(Ab + aOff[h] + (size_t)(kt) * 128, d_);                              \
    load16(Ab + aOff[h] + ROW64 + (size_t)(kt) * 128, d_ + 8192);               \
  } while (0)
#define STAGE_B(b, h, kt) do {                                                  \
    char* d_ = ldsB + (((b) * 4 + 2 + (h)) * 16384) + wave * 1024;              \
    load16(Bb + bOff[h] + (size_t)(kt) * 128, d_);                              \
    load16(Bb + bOff[h] + ROW64 + (size_t)(kt) * 128, d_ + 8192);               \
  } while (0)

  // ---- fragment reads (swizzled): row stride 128 B, slot ^= row&7 (row&7==l16&7)
  const int sw = (l16 & 7) << 4;
  const int ca0 = (quad * 16) ^ sw;        // kk=0 col-byte
  const int ca1 = (64 + quad * 16) ^ sw;   // kk=1 col-byte
  const char* aBase = ldsB + wr * 16384 + l16 * 128;
  const char* bBase = ldsB + (2 + (wc >> 1)) * 16384 + ((wc & 1) * 64 + l16) * 128;

  const f32x4 fz = {0.f, 0.f, 0.f, 0.f};
  f32x4 acc[8][4];
#pragma unroll
  for (int i = 0; i < 8; ++i)
#pragma unroll
    for (int j = 0; j < 4; ++j) acc[i][j] = fz;
  bf16x8 af[8], bfv[8];

#define LDA(b, mb) do {                                                         \
    _Pragma("unroll") for (int m4 = 0; m4 < 4; ++m4) {                          \
      af[m4 * 2 + 0] = *(const bf16x8*)(aBase + (b) * 65536 + ((mb) + m4) * 2048 + ca0); \
      af[m4 * 2 + 1] = *(const bf16x8*)(aBase + (b) * 65536 + ((mb) + m4) * 2048 + ca1); \
    } } while (0)
#define LDB_ALL(b) do {                                                         \
    _Pragma("unroll") for (int n4 = 0; n4 < 4; ++n4) {                          \
      bfv[n4 * 2 + 0] = *(const bf16x8*)(bBase + (b) * 65536 + n4 * 2048 + ca0); \
      bfv[n4 * 2 + 1] = *(const bf16x8*)(bBase + (b) * 65536 + n4 * 2048 + ca1); \
    } } while (0)
#define MMQ(mh, nh) do {                                                        \
    __builtin_amdgcn_s_setprio(1);                                              \
    _Pragma("unroll") for (int m4 = 0; m4 < 4; ++m4)                            \
    _Pragma("unroll") for (int n2 = 0; n2 < 2; ++n2)                            \
    _Pragma("unroll") for (int kk = 0; kk < 2; ++kk)                            \
      acc[(mh) * 4 + m4][(nh) * 2 + n2] = __builtin_amdgcn_mfma_f32_16x16x32_bf16( \
          af[m4 * 2 + kk], bfv[((nh) * 2 + n2) * 2 + kk],                       \
          acc[(mh) * 4 + m4][(nh) * 2 + n2], 0, 0, 0);                          \
    __builtin_amdgcn_s_setprio(0);                                              \
  } while (0)
#define BAR() __builtin_amdgcn_s_barrier()
#define VMCNT6() asm volatile("s_waitcnt vmcnt(6)" ::: "memory")

  // ---- prologue: Kt0.B0,B1,A0,A1, Kt1.B0,B1,A0 (7 half-tiles = steady-state
  // history), then vmcnt(6): Kt0 resident, 3 half-tiles of Kt1 in flight.
  STAGE_B(0, 0, 0); STAGE_B(0, 1, 0);
  STAGE_A(0, 0, 0); STAGE_A(0, 1, 0);
  STAGE_B(1, 0, 1); STAGE_B(1, 1, 1);
  STAGE_A(1, 0, 1);
  VMCNT6();
  BAR();

  const int NIT = K >> 7;  // 2 K-tiles (2x64) per iteration
#pragma unroll 1
  for (int i = 0; i < NIT; ++i) {
    const int t0 = i * 2;
    // ---- K-tile 2i (buf0) ----
    // P1 (of 8): 16 ds_reads + finish Kt2i+1 staging
    LDA(0, 0); LDB_ALL(0); STAGE_A(1, 1, t0 + 1); BAR(); MMQ(0, 0); BAR();
    // P2
    STAGE_B(0, 0, t0 + 2); BAR(); MMQ(0, 1); BAR();
    // P3
    LDA(0, 4); STAGE_B(0, 1, t0 + 2); BAR(); MMQ(1, 0); BAR();
    // P4: counted wait -> Kt2i+1 fully resident (3 newest halves may fly)
    STAGE_A(0, 0, t0 + 2); VMCNT6(); BAR(); MMQ(1, 1); BAR();
    // ---- K-tile 2i+1 (buf1) ----
    // P5
    LDA(1, 0); LDB_ALL(1); STAGE_A(0, 1, t0 + 2); BAR(); MMQ(0, 0); BAR();
    // P6
    STAGE_B(1, 0, t0 + 3); BAR(); MMQ(0, 1); BAR();
    // P7
    LDA(1, 4); STAGE_B(1, 1, t0 + 3); BAR(); MMQ(1, 0); BAR();
    // P8: counted wait -> Kt2i+2 fully resident
    STAGE_A(1, 0, t0 + 3); VMCNT6(); BAR(); MMQ(1, 1); BAR();
  }

#undef STAGE_A
#undef STAGE_B
#undef LDA
#undef LDB_ALL
#undef MMQ
#undef BAR
#undef VMCNT6

  // ---- epilogue: C/D layout col=lane&15, row=quad*4+t ----
  const int row0 = m0 + wr * 128 + quad * 4;
  const int col0 = n0 + wc * 64 + l16;
#pragma unroll
  for (int m = 0; m < 8; ++m) {
    const int rb = row0 + m * 16;
#pragma unroll
    for (int n = 0; n < 4; ++n) {
      const int col = col0 + n * 16;
      const float bv = bias[col];
#pragma unroll
      for (int t = 0; t < 4; ++t) {
        float v = acc[m][n][t] + bv;
        size_t idx = (size_t)(rb + t) * N + col;
        if (EPI == 1) {
          ((float*)out)[idx] = v + res[idx];
        } else {
          ((u16*)out)[idx] = f2bf(v);
        }
      }
    }
  }
}

// ---------------- flash attention (v2: swizzled LDS + pipelined K) ----------------
// grid (S/64, B*H), block 256 (4 waves). Wave w owns q rows [q0+16w, +16).
// LDS: Kbuf[2] (16 KB each, 64x128 bf16, chunk^(row&15) swizzle)
//      Vbuf    (16 KB, 128x64 bf16, chunk^(row&7) swizzle)
//      Ps      (64 x stride-72 bf16, wave-private rows)
__global__ __launch_bounds__(256) void flash_attn(const u16* __restrict__ fused,
                                                  const u16* __restrict__ vt,
                                                  const float* __restrict__ alibi,
                                                  u16* __restrict__ ctx) {
  __shared__ __align__(16) u16 Kbuf[2][64 * 128];
  __shared__ __align__(16) u16 Vbuf[128 * 64];
  __shared__ __align__(16) u16 Ps[64 * 72];

  const int tid = threadIdx.x, wave = tid >> 6, lane = tid & 63;
  const int quad = lane >> 4, l16 = lane & 15;
  const int qt = blockIdx.x, bh = blockIdx.y;
  const int b = bh >> 5, h = bh & 31;
  const int q0 = qt * 64;
  const float scale = 0.08838834764831845f;  // 1/sqrt(128)
  const f32x4 fz = {0.f, 0.f, 0.f, 0.f};

  // --- precomputed per-lane staging sources ---
  const u16* srcQ[4];
  const u16* srcK[4];  // row-relative (add kv0*12288 per tile)
  for (int j = 0; j < 4; ++j) {
    int inst = wave * 4 + j;
    int row = inst * 4 + quad;
    int cg = l16 ^ (row & 15);
    srcQ[j] = fused + (size_t)(b * 2048 + q0 + row) * 12288 + h * 384 + cg * 8;
    srcK[j] = fused + (size_t)(b * 2048 + row) * 12288 + h * 384 + 128 + cg * 8;
  }
  const u16* srcV[4];  // add kv0 per tile
  for (int j = 0; j < 4; ++j) {
    int inst = wave * 4 + j;
    int row = inst * 8 + (lane >> 3);
    int cg = (lane & 7) ^ (row & 7);
    srcV[j] = vt + ((size_t)bh * 128 + row) * 2048 + cg * 8;
  }

  // --- prologue: stage Q into Kbuf[1], K tile 0 into Kbuf[0] ---
  for (int j = 0; j < 4; ++j) {
    int inst = wave * 4 + j;
    load16(srcQ[j], (char*)Kbuf[1] + inst * 1024);
    load16(srcK[j], (char*)Kbuf[0] + inst * 1024);
  }
  __syncthreads();  // drains vmcnt: Q + K0 resident

  // Q fragments -> registers (swizzled read, 2-way banks = free)
  bf16x8 qf[4];
  for (int kk = 0; kk < 4; ++kk) {
    int row = wave * 16 + l16;
    int cs = (kk * 4 + quad) ^ l16;
    qf[kk] = *(const bf16x8*)((const char*)Kbuf[1] + row * 256 + cs * 16);
  }
  __syncthreads();  // all waves own their Q frags before Kbuf[1] is re-staged

  float m_st[4] = {-__builtin_inff(), -__builtin_inff(), -__builtin_inff(), -__builtin_inff()};
  float l_st[4] = {0.f, 0.f, 0.f, 0.f};
  f32x4 o_acc[8];
  for (int f = 0; f < 8; ++f) o_acc[f] = fz;

  const int nkv = qt + 1;  // causal
  for (int kvt = 0; kvt < nkv; ++kvt) {
    const int kv0 = kvt * 64;
    const int cur = kvt & 1;

    for (int j = 0; j < 4; ++j) {
      int inst = wave * 4 + j;
      load16(srcV[j] + kv0, (char*)Vbuf + inst * 1024);
    }
    if (kvt + 1 < nkv) {
      for (int j = 0; j < 4; ++j) {
        int inst = wave * 4 + j;
        load16(srcK[j] + (size_t)(kv0 + 64) * 12288, (char*)Kbuf[cur ^ 1] + inst * 1024);
      }
    }

    // S = Q K^T : per wave 16q x 64kv
    f32x4 sa[4];
    for (int j = 0; j < 4; ++j) sa[j] = fz;
    for (int kk = 0; kk < 4; ++kk) {
      for (int j = 0; j < 4; ++j) {
        int row = j * 16 + l16;
        int cs = (kk * 4 + quad) ^ l16;
        bf16x8 bv = *(const bf16x8*)((const char*)Kbuf[cur] + row * 256 + cs * 16);
        sa[j] = __builtin_amdgcn_mfma_f32_16x16x32_bf16(qf[kk], bv, sa[j], 0, 0, 0);
      }
    }

    // scale + alibi + causal mask
    float al[4];
    for (int j = 0; j < 4; ++j) al[j] = alibi[(size_t)bh * 2048 + kv0 + j * 16 + l16];
    float p[4][4];
    const bool diag = (kvt == qt);
    for (int j = 0; j < 4; ++j) {
      int kvg = kv0 + j * 16 + l16;
      for (int t = 0; t < 4; ++t) {
        float v = sa[j][t] * scale + al[j];
        if (diag) {
          int qg = q0 + wave * 16 + quad * 4 + t;
          if (kvg > qg) v = -__builtin_inff();
        }
        p[j][t] = v;
      }
    }

    // online softmax (row r = quad*4+t lives in the 16 lanes sharing quad)
    float mnew[4], alpha[4];
    for (int t = 0; t < 4; ++t) {
      float mx = fmaxf(fmaxf(p[0][t], p[1][t]), fmaxf(p[2][t], p[3][t]));
      for (int off = 1; off < 16; off <<= 1) mx = fmaxf(mx, __shfl_xor(mx, off, 64));
      mnew[t] = fmaxf(m_st[t], mx);
      alpha[t] = __expf(m_st[t] - mnew[t]);
      m_st[t] = mnew[t];
      float rs = 0.f;
      for (int j = 0; j < 4; ++j) {
        p[j][t] = __expf(p[j][t] - mnew[t]);
        rs += p[j][t];
      }
      for (int off = 1; off < 16; off <<= 1) rs += __shfl_xor(rs, off, 64);
      l_st[t] = l_st[t] * alpha[t] + rs;
    }
    for (int f = 0; f < 8; ++f)
      for (int t = 0; t < 4; ++t) o_acc[f][t] *= alpha[t];

    // P: C-layout -> A-layout via LDS (wave-private rows, stride 72 => 2-way banks)
    for (int j = 0; j < 4; ++j)
      for (int t = 0; t < 4; ++t)
        Ps[(wave * 16 + quad * 4 + t) * 72 + j * 16 + l16] = f2bf(p[j][t]);

    __syncthreads();  // MID: drains V(kvt) (+K(kvt+1)) staging — hidden by QK+softmax

    // O += P V  (A from Ps, B from swizzled Vbuf)
    for (int kk = 0; kk < 2; ++kk) {
      bf16x8 a = *(const bf16x8*)((const char*)Ps + ((wave * 16 + l16) * 72 + kk * 32 + quad * 8) * 2);
      for (int f = 0; f < 8; ++f) {
        int row = f * 16 + l16;
        int cs = (kk * 4 + quad) ^ (l16 & 7);
        bf16x8 bv = *(const bf16x8*)((const char*)Vbuf + row * 128 + cs * 16);
        o_acc[f] = __builtin_amdgcn_mfma_f32_16x16x32_bf16(a, bv, o_acc[f], 0, 0, 0);
      }
    }

    __syncthreads();  // END: Vbuf readers done (cheap: no loads in flight since MID)
  }

  // epilogue: ctx[b,s,h*128+d] bf16
  float invl[4];
  for (int t = 0; t < 4; ++t) invl[t] = 1.0f / l_st[t];
  for (int f = 0; f < 8; ++f) {
    int d = h * 128 + f * 16 + l16;
    for (int t = 0; t < 4; ++t) {
      int row = b * 2048 + q0 + wave * 16 + quad * 4 + t;
      ctx[(size_t)row * 4096 + d] = f2bf(o_acc[f][t] * invl[t]);
    }
  }
}

// ---------------- launch ----------------
extern "C" void kernel_launch(void* const* d_in, const int* in_sizes, int n_in,
                              void* d_out, int out_size, void* d_ws, size_t ws_size,
                              hipStream_t stream) {
  const float* hs    = (const float*)d_in[0];
  const float* resid = (const float*)d_in[1];
  const float* alibi = (const float*)d_in[2];
  // d_in[3] = attention_mask: deterministic causal, computed analytically
  const float* Wqkv  = (const float*)d_in[4];
  const float* bqkv  = (const float*)d_in[5];
  const float* Wd    = (const float*)d_in[6];
  const float* bd    = (const float*)d_in[7];

  char* ws = (char*)d_ws;
  u16* Abf   = (u16*)(ws);                        // 32 MB
  u16* W1T   = (u16*)(ws + (size_t)33554432);     // 96 MB
  u16* fused = (u16*)(ws + (size_t)134217728);    // 96 MB
  u16* vtb   = (u16*)(ws + (size_t)234881024);    // 32 MB
  u16* ctx   = (u16*)(ws);                        // reuse Abf (dead after GEMM1)
  u16* W2T   = (u16*)(ws + (size_t)33554432);     // reuse W1T (dead after GEMM1)

  cvt_bf16<<<16384, 256, 0, stream>>>(hs, Abf, 16777216);
  cvt_transpose<<<dim3(384, 128), 256, 0, stream>>>(Wqkv, W1T, 4096, 12288);
  // GEMM1: M=4096, N=12288 -> 16 x 48 = 768 tiles (768 % 8 == 0)
  gemm256<0><<<dim3(768), 512, 0, stream>>>(Abf, W1T, bqkv, nullptr, fused, 4096, 12288, 4096);
  transpose_v<<<dim3(32, 64), 256, 0, stream>>>(fused, vtb);
  cvt_transpose<<<dim3(128, 128), 256, 0, stream>>>(Wd, W2T, 4096, 4096);  // after GEMM1 read of W1T
  flash_attn<<<dim3(32, 64), 256, 0, stream>>>(fused, vtb, alibi, ctx);    // ctx overwrites Abf after GEMM1
  // GEMM2: 16 x 16 = 256 tiles (256 % 8 == 0)
  gemm256<1><<<dim3(256), 512, 0, stream>>>(ctx, W2T, bd, resid, d_out, 4096, 4096, 4096);
}

// Round 2
// 1286.848 us; speedup vs baseline: 1.1820x; 1.1820x over previous
//
#include <hip/hip_runtime.h>
#include <cstdint>
#include <cstddef>

// BloomAttention MI355X implementation.
// Round 4: gemm256 LDS split into FOUR distinct __shared__ objects
// (ldsA0/ldsA1/ldsB0/ldsB1). Rationale: LLVM SIInsertWaitcnts tracks LDS-DMA
// (global_load_lds) writes by memoperand and inserts conservative vmcnt waits
// before aliasing ds_reads; with one big lds[] every phase's ds_read aliased
// every in-flight stage -> effective vmcnt(0) per phase -> measured 690 TF
// (exactly the 2-phase/full-drain regime, vs 1167-1563 for true counted
// 8-phase). Distinct objects => alias sets per operand => the ledger already
// guarantees those DMAs are drained by the previous vmcnt(6) => inserted
// waits become no-ops. Also: B-fragment reads split LDB_LO(P1)/LDB_HI(P2)
// to match the verified template's {12,4,8,0} per-phase read distribution.
// Schedule skeleton (barriers, vmcnt placement, swizzle, MMQ order) UNCHANGED.
//
// Overwrite/residency ledger (per iter, K-tiles 2i->buf0, 2i+1->buf1):
//   stages: P1:Kt2i+1.A1  P2:Kt2i+2.B0  P3:Kt2i+2.B1  P4:Kt2i+2.A0 [vmcnt6]
//           P5:Kt2i+2.A1  P6:Kt2i+3.B0  P7:Kt2i+3.B1  P8:Kt2i+3.A0 [vmcnt6]
//   vmcnt(6) at P4 leaves {Kt2i+2.B0,B1,A0} in flight (buf0 stages for NEXT
//   iter) and guarantees all buf1 (Kt2i+1) DMAs landed before P5's reads;
//   vmcnt(6) at P8 mirrors for buf0/Kt2i+2. Every ds_read's aliasing DMAs
//   are therefore always already drained at read time.
// flash_attn / transposes unchanged from round 2.
//
// Workspace layout (256 MB, liveness overlap):
//   [0,32M)    A_bf16   (later reused as ctx)
//   [32,128M)  W1T      (later reused as W2T)
//   [128,224M) fused
//   [224,256M) VT

typedef unsigned short u16;
typedef unsigned int u32;
typedef __bf16 bf16x8 __attribute__((ext_vector_type(8)));
typedef float f32x4 __attribute__((ext_vector_type(4)));
typedef u16 u16x4 __attribute__((ext_vector_type(4)));

#define LDS_AS(p) ((__attribute__((address_space(3))) u32*)(p))
#define GLB_AS(p) ((__attribute__((address_space(1))) u32*)(p))

// async global->LDS, 16B per lane; LDS dest = wave-uniform base + lane*16,
// global source is PER-LANE (this is what makes the XOR swizzle possible).
__device__ __forceinline__ void load16(const void* g, void* l) {
  __builtin_amdgcn_global_load_lds(GLB_AS(g), LDS_AS(l), 16, 0, 0);
}

__device__ __forceinline__ u16 f2bf(float f) {
  union { float f; u32 u; } x; x.f = f;
  u32 r = x.u + 0x7fffu + ((x.u >> 16) & 1u);  // RNE
  return (u16)(r >> 16);
}

// ---------------- elementwise f32 -> bf16 ----------------
__global__ __launch_bounds__(256) void cvt_bf16(const float* __restrict__ in,
                                                u16* __restrict__ out, int n) {
  int i = (blockIdx.x * 256 + threadIdx.x) * 4;
  if (i >= n) return;
  float4 v = *(const float4*)(in + i);
  u16x4 o = { f2bf(v.x), f2bf(v.y), f2bf(v.z), f2bf(v.w) };
  *(u16x4*)(out + i) = o;
}

// ---------------- f32 [K][N] -> bf16 [N][K] (transpose+convert) ----------------
__global__ __launch_bounds__(256) void cvt_transpose(const float* __restrict__ W,
                                                     u16* __restrict__ WT,
                                                     int K, int N) {
  __shared__ float tile[32][33];
  int n0 = blockIdx.x * 32, k0 = blockIdx.y * 32;
  int tx = threadIdx.x & 31, ty = threadIdx.x >> 5;  // 32 x 8
  for (int r = ty; r < 32; r += 8)
    tile[r][tx] = W[(size_t)(k0 + r) * N + n0 + tx];
  __syncthreads();
  for (int r = ty; r < 32; r += 8)
    WT[(size_t)(n0 + r) * K + k0 + tx] = f2bf(tile[tx][r]);
}

// ---------------- V slice of fused -> VT[B*H][HD][S] ----------------
__global__ __launch_bounds__(256) void transpose_v(const u16* __restrict__ fused,
                                                   u16* __restrict__ vt) {
  __shared__ __align__(16) u16 tile[64][136];
  int st = blockIdx.x * 64, bh = blockIdx.y;
  int b = bh >> 5, h = bh & 31;
  int tx = threadIdx.x & 15, ty = threadIdx.x >> 4;  // 16 x 16
  for (int r = ty; r < 64; r += 16) {
    const u16* src = fused + (size_t)(b * 2048 + st + r) * 12288 + h * 384 + 256 + tx * 8;
    u16x4 a = *(const u16x4*)(src);
    u16x4 c = *(const u16x4*)(src + 4);
    *(u16x4*)&tile[r][tx * 8] = a;
    *(u16x4*)&tile[r][tx * 8 + 4] = c;
  }
  __syncthreads();
  for (int d = ty; d < 128; d += 16) {
    u16x4 o = { tile[tx * 4 + 0][d], tile[tx * 4 + 1][d],
                tile[tx * 4 + 2][d], tile[tx * 4 + 3][d] };
    *(u16x4*)(vt + ((size_t)bh * 128 + d) * 2048 + st + tx * 4) = o;
  }
}

// ---------------- 256x256 8-phase bf16 GEMM: C = A[M,K] * BT[N,K]^T + bias (+res) ----
// EPI 0: out bf16.  EPI 1: out f32 with +residual.
// Requires: M%256==0, N%256==0, K%128==0, grid 1-D with nwg%8==0.
template <int EPI>
__global__ __launch_bounds__(512, 2) void gemm256(const u16* __restrict__ A,
                                                  const u16* __restrict__ BT,
                                                  const float* __restrict__ bias,
                                                  const float* __restrict__ res,
                                                  void* __restrict__ out,
                                                  int M, int N, int K) {
  // Four DISTINCT LDS objects (one per double-buffer operand) so the
  // compiler's LDS-DMA alias tracking can disambiguate stage-vs-read.
  // Each: [half h][128 rows][64 cols bf16] = 32 KB; total 128 KiB.
  __shared__ __align__(16) u16 ldsA0[16384];
  __shared__ __align__(16) u16 ldsA1[16384];
  __shared__ __align__(16) u16 ldsB0[16384];
  __shared__ __align__(16) u16 ldsB1[16384];

  const int tid = threadIdx.x, wave = tid >> 6, lane = tid & 63;
  const int quad = lane >> 4, l16 = lane & 15;
  const int wr = wave >> 2, wc = wave & 3;  // 2 x 4 wave grid

  // XCD-aware swizzle (bijective since nwg % 8 == 0)
  const int nwg = gridDim.x, per = nwg >> 3, bid = blockIdx.x;
  const int swz = (bid & 7) * per + (bid >> 3);
  const int ntn = N >> 8;
  const int tm = swz / ntn, tn = swz - tm * ntn;
  const int m0 = tm << 8, n0 = tn << 8;

  // ---- staging geometry: half-tile = 128x64 bf16 = 16 KB = 2 insts x 8 KB.
  // inst j covers LDS bytes [j*8192 +wave*1024 +lane*16); row = j*64+wave*8+lane>>3,
  // 16B slot = lane&7. Source slot = lds_slot ^ (row&7)  (inverse XOR swizzle).
  const int r0 = wave * 8 + (lane >> 3);
  const int scb = ((lane & 7) ^ ((lane >> 3) & 7)) << 4;
  const char* Ab = (const char*)A;
  const char* Bb = (const char*)BT;
  const size_t ROW64 = (size_t)K * 128;  // 64 rows of bf16 [*][K]
  size_t aOff[2], bOff[2];
#pragma unroll
  for (int h = 0; h < 2; ++h) {
    aOff[h] = ((size_t)(m0 + h * 128 + r0) * K) * 2 + scb;
    bOff[h] = ((size_t)(n0 + h * 128 + r0) * K) * 2 + scb;
  }

#define STAGE_A(b, h, kt) do {                                                  \
    char* d_ = (char*)ldsA##b + (h) * 16384 + wave * 1024;                      \
    load16(Ab + aOff[h] + (size_t)(kt) * 128, d_);                              \
    load16(Ab + aOff[h] + ROW64 + (size_t)(kt) * 128, d_ + 8192);               \
  } while (0)
#define STAGE_B(b, h, kt) do {                                                  \
    char* d_ = (char*)ldsB##b + (h) * 16384 + wave * 1024;                      \
    load16(Bb + bOff[h] + (size_t)(kt) * 128, d_);                              \
    load16(Bb + bOff[h] + ROW64 + (size_t)(kt) * 128, d_ + 8192);               \
  } while (0)

  // ---- fragment reads (swizzled): row stride 128 B, slot ^= row&7 (row&7==l16&7)
  const int sw = (l16 & 7) << 4;
  const int ca0 = (quad * 16) ^ sw;        // kk=0 col-byte
  const int ca1 = (64 + quad * 16) ^ sw;   // kk=1 col-byte
  const char* aB0 = (const char*)ldsA0 + wr * 16384 + l16 * 128;
  const char* aB1 = (const char*)ldsA1 + wr * 16384 + l16 * 128;
  const char* bB0 = (const char*)ldsB0 + (wc >> 1) * 16384 + ((wc & 1) * 64 + l16) * 128;
  const char* bB1 = (const char*)ldsB1 + (wc >> 1) * 16384 + ((wc & 1) * 64 + l16) * 128;

  const f32x4 fz = {0.f, 0.f, 0.f, 0.f};
  f32x4 acc[8][4];
#pragma unroll
  for (int i = 0; i < 8; ++i)
#pragma unroll
    for (int j = 0; j < 4; ++j) acc[i][j] = fz;
  bf16x8 af[8], bfv[8];

#define LDA(b, mb) do {                                                         \
    _Pragma("unroll") for (int m4 = 0; m4 < 4; ++m4) {                          \
      af[m4 * 2 + 0] = *(const bf16x8*)(aB##b + ((mb) + m4) * 2048 + ca0);      \
      af[m4 * 2 + 1] = *(const bf16x8*)(aB##b + ((mb) + m4) * 2048 + ca1);      \
    } } while (0)
#define LDB_LO(b) do {                                                          \
    _Pragma("unroll") for (int n4 = 0; n4 < 2; ++n4) {                          \
      bfv[n4 * 2 + 0] = *(const bf16x8*)(bB##b + n4 * 2048 + ca0);              \
      bfv[n4 * 2 + 1] = *(const bf16x8*)(bB##b + n4 * 2048 + ca1);              \
    } } while (0)
#define LDB_HI(b) do {                                                          \
    _Pragma("unroll") for (int n4 = 2; n4 < 4; ++n4) {                          \
      bfv[n4 * 2 + 0] = *(const bf16x8*)(bB##b + n4 * 2048 + ca0);              \
      bfv[n4 * 2 + 1] = *(const bf16x8*)(bB##b + n4 * 2048 + ca1);              \
    } } while (0)
#define MMQ(mh, nh) do {                                                        \
    __builtin_amdgcn_s_setprio(1);                                              \
    _Pragma("unroll") for (int m4 = 0; m4 < 4; ++m4)                            \
    _Pragma("unroll") for (int n2 = 0; n2 < 2; ++n2)                            \
    _Pragma("unroll") for (int kk = 0; kk < 2; ++kk)                            \
      acc[(mh) * 4 + m4][(nh) * 2 + n2] = __builtin_amdgcn_mfma_f32_16x16x32_bf16( \
          af[m4 * 2 + kk], bfv[((nh) * 2 + n2) * 2 + kk],                       \
          acc[(mh) * 4 + m4][(nh) * 2 + n2], 0, 0, 0);                          \
    __builtin_amdgcn_s_setprio(0);                                              \
  } while (0)
#define BAR() __builtin_amdgcn_s_barrier()
#define VMCNT6() asm volatile("s_waitcnt vmcnt(6)" ::: "memory")

  // ---- prologue: Kt0.B0,B1,A0,A1, Kt1.B0,B1,A0 (7 half-tiles = steady-state
  // history), then vmcnt(6): Kt0 resident, 3 half-tiles of Kt1 in flight.
  STAGE_B(0, 0, 0); STAGE_B(0, 1, 0);
  STAGE_A(0, 0, 0); STAGE_A(0, 1, 0);
  STAGE_B(1, 0, 1); STAGE_B(1, 1, 1);
  STAGE_A(1, 0, 1);
  VMCNT6();
  BAR();

  const int NIT = K >> 7;  // 2 K-tiles (2x64) per iteration
#pragma unroll 1
  for (int i = 0; i < NIT; ++i) {
    const int t0 = i * 2;
    // ---- K-tile 2i (buf0) ----
    // P1: 12 ds_reads (A-half0 + B-lo) + finish Kt2i+1 staging
    LDA(0, 0); LDB_LO(0); STAGE_A(1, 1, t0 + 1); BAR(); MMQ(0, 0); BAR();
    // P2: 4 ds_reads (B-hi)
    LDB_HI(0); STAGE_B(0, 0, t0 + 2); BAR(); MMQ(0, 1); BAR();
    // P3: 8 ds_reads (A-half1)
    LDA(0, 4); STAGE_B(0, 1, t0 + 2); BAR(); MMQ(1, 0); BAR();
    // P4: counted wait -> Kt2i+1 fully resident (3 newest halves may fly)
    STAGE_A(0, 0, t0 + 2); VMCNT6(); BAR(); MMQ(1, 1); BAR();
    // ---- K-tile 2i+1 (buf1) ----
    // P5
    LDA(1, 0); LDB_LO(1); STAGE_A(0, 1, t0 + 2); BAR(); MMQ(0, 0); BAR();
    // P6
    LDB_HI(1); STAGE_B(1, 0, t0 + 3); BAR(); MMQ(0, 1); BAR();
    // P7
    LDA(1, 4); STAGE_B(1, 1, t0 + 3); BAR(); MMQ(1, 0); BAR();
    // P8: counted wait -> Kt2i+2 fully resident
    STAGE_A(1, 0, t0 + 3); VMCNT6(); BAR(); MMQ(1, 1); BAR();
  }

#undef STAGE_A
#undef STAGE_B
#undef LDA
#undef LDB_LO
#undef LDB_HI
#undef MMQ
#undef BAR
#undef VMCNT6

  // ---- epilogue: C/D layout col=lane&15, row=quad*4+t ----
  const int row0 = m0 + wr * 128 + quad * 4;
  const int col0 = n0 + wc * 64 + l16;
#pragma unroll
  for (int m = 0; m < 8; ++m) {
    const int rb = row0 + m * 16;
#pragma unroll
    for (int n = 0; n < 4; ++n) {
      const int col = col0 + n * 16;
      const float bv = bias[col];
#pragma unroll
      for (int t = 0; t < 4; ++t) {
        float v = acc[m][n][t] + bv;
        size_t idx = (size_t)(rb + t) * N + col;
        if (EPI == 1) {
          ((float*)out)[idx] = v + res[idx];
        } else {
          ((u16*)out)[idx] = f2bf(v);
        }
      }
    }
  }
}

// ---------------- flash attention (v2: swizzled LDS + pipelined K) ----------------
// grid (S/64, B*H), block 256 (4 waves). Wave w owns q rows [q0+16w, +16).
// LDS: Kbuf[2] (16 KB each, 64x128 bf16, chunk^(row&15) swizzle)
//      Vbuf    (16 KB, 128x64 bf16, chunk^(row&7) swizzle)
//      Ps      (64 x stride-72 bf16, wave-private rows)
__global__ __launch_bounds__(256) void flash_attn(const u16* __restrict__ fused,
                                                  const u16* __restrict__ vt,
                                                  const float* __restrict__ alibi,
                                                  u16* __restrict__ ctx) {
  __shared__ __align__(16) u16 Kbuf[2][64 * 128];
  __shared__ __align__(16) u16 Vbuf[128 * 64];
  __shared__ __align__(16) u16 Ps[64 * 72];

  const int tid = threadIdx.x, wave = tid >> 6, lane = tid & 63;
  const int quad = lane >> 4, l16 = lane & 15;
  const int qt = blockIdx.x, bh = blockIdx.y;
  const int b = bh >> 5, h = bh & 31;
  const int q0 = qt * 64;
  const float scale = 0.08838834764831845f;  // 1/sqrt(128)
  const f32x4 fz = {0.f, 0.f, 0.f, 0.f};

  // --- precomputed per-lane staging sources ---
  const u16* srcQ[4];
  const u16* srcK[4];  // row-relative (add kv0*12288 per tile)
  for (int j = 0; j < 4; ++j) {
    int inst = wave * 4 + j;
    int row = inst * 4 + quad;
    int cg = l16 ^ (row & 15);
    srcQ[j] = fused + (size_t)(b * 2048 + q0 + row) * 12288 + h * 384 + cg * 8;
    srcK[j] = fused + (size_t)(b * 2048 + row) * 12288 + h * 384 + 128 + cg * 8;
  }
  const u16* srcV[4];  // add kv0 per tile
  for (int j = 0; j < 4; ++j) {
    int inst = wave * 4 + j;
    int row = inst * 8 + (lane >> 3);
    int cg = (lane & 7) ^ (row & 7);
    srcV[j] = vt + ((size_t)bh * 128 + row) * 2048 + cg * 8;
  }

  // --- prologue: stage Q into Kbuf[1], K tile 0 into Kbuf[0] ---
  for (int j = 0; j < 4; ++j) {
    int inst = wave * 4 + j;
    load16(srcQ[j], (char*)Kbuf[1] + inst * 1024);
    load16(srcK[j], (char*)Kbuf[0] + inst * 1024);
  }
  __syncthreads();  // drains vmcnt: Q + K0 resident

  // Q fragments -> registers (swizzled read, 2-way banks = free)
  bf16x8 qf[4];
  for (int kk = 0; kk < 4; ++kk) {
    int row = wave * 16 + l16;
    int cs = (kk * 4 + quad) ^ l16;
    qf[kk] = *(const bf16x8*)((const char*)Kbuf[1] + row * 256 + cs * 16);
  }
  __syncthreads();  // all waves own their Q frags before Kbuf[1] is re-staged

  float m_st[4] = {-__builtin_inff(), -__builtin_inff(), -__builtin_inff(), -__builtin_inff()};
  float l_st[4] = {0.f, 0.f, 0.f, 0.f};
  f32x4 o_acc[8];
  for (int f = 0; f < 8; ++f) o_acc[f] = fz;

  const int nkv = qt + 1;  // causal
  for (int kvt = 0; kvt < nkv; ++kvt) {
    const int kv0 = kvt * 64;
    const int cur = kvt & 1;

    for (int j = 0; j < 4; ++j) {
      int inst = wave * 4 + j;
      load16(srcV[j] + kv0, (char*)Vbuf + inst * 1024);
    }
    if (kvt + 1 < nkv) {
      for (int j = 0; j < 4; ++j) {
        int inst = wave * 4 + j;
        load16(srcK[j] + (size_t)(kv0 + 64) * 12288, (char*)Kbuf[cur ^ 1] + inst * 1024);
      }
    }

    // S = Q K^T : per wave 16q x 64kv
    f32x4 sa[4];
    for (int j = 0; j < 4; ++j) sa[j] = fz;
    for (int kk = 0; kk < 4; ++kk) {
      for (int j = 0; j < 4; ++j) {
        int row = j * 16 + l16;
        int cs = (kk * 4 + quad) ^ l16;
        bf16x8 bv = *(const bf16x8*)((const char*)Kbuf[cur] + row * 256 + cs * 16);
        sa[j] = __builtin_amdgcn_mfma_f32_16x16x32_bf16(qf[kk], bv, sa[j], 0, 0, 0);
      }
    }

    // scale + alibi + causal mask
    float al[4];
    for (int j = 0; j < 4; ++j) al[j] = alibi[(size_t)bh * 2048 + kv0 + j * 16 + l16];
    float p[4][4];
    const bool diag = (kvt == qt);
    for (int j = 0; j < 4; ++j) {
      int kvg = kv0 + j * 16 + l16;
      for (int t = 0; t < 4; ++t) {
        float v = sa[j][t] * scale + al[j];
        if (diag) {
          int qg = q0 + wave * 16 + quad * 4 + t;
          if (kvg > qg) v = -__builtin_inff();
        }
        p[j][t] = v;
      }
    }

    // online softmax (row r = quad*4+t lives in the 16 lanes sharing quad)
    float mnew[4], alpha[4];
    for (int t = 0; t < 4; ++t) {
      float mx = fmaxf(fmaxf(p[0][t], p[1][t]), fmaxf(p[2][t], p[3][t]));
      for (int off = 1; off < 16; off <<= 1) mx = fmaxf(mx, __shfl_xor(mx, off, 64));
      mnew[t] = fmaxf(m_st[t], mx);
      alpha[t] = __expf(m_st[t] - mnew[t]);
      m_st[t] = mnew[t];
      float rs = 0.f;
      for (int j = 0; j < 4; ++j) {
        p[j][t] = __expf(p[j][t] - mnew[t]);
        rs += p[j][t];
      }
      for (int off = 1; off < 16; off <<= 1) rs += __shfl_xor(rs, off, 64);
      l_st[t] = l_st[t] * alpha[t] + rs;
    }
    for (int f = 0; f < 8; ++f)
      for (int t = 0; t < 4; ++t) o_acc[f][t] *= alpha[t];

    // P: C-layout -> A-layout via LDS (wave-private rows, stride 72 => 2-way banks)
    for (int j = 0; j < 4; ++j)
      for (int t = 0; t < 4; ++t)
        Ps[(wave * 16 + quad * 4 + t) * 72 + j * 16 + l16] = f2bf(p[j][t]);

    __syncthreads();  // MID: drains V(kvt) (+K(kvt+1)) staging — hidden by QK+softmax

    // O += P V  (A from Ps, B from swizzled Vbuf)
    for (int kk = 0; kk < 2; ++kk) {
      bf16x8 a = *(const bf16x8*)((const char*)Ps + ((wave * 16 + l16) * 72 + kk * 32 + quad * 8) * 2);
      for (int f = 0; f < 8; ++f) {
        int row = f * 16 + l16;
        int cs = (kk * 4 + quad) ^ (l16 & 7);
        bf16x8 bv = *(const bf16x8*)((const char*)Vbuf + row * 128 + cs * 16);
        o_acc[f] = __builtin_amdgcn_mfma_f32_16x16x32_bf16(a, bv, o_acc[f], 0, 0, 0);
      }
    }

    __syncthreads();  // END: Vbuf readers done (cheap: no loads in flight since MID)
  }

  // epilogue: ctx[b,s,h*128+d] bf16
  float invl[4];
  for (int t = 0; t < 4; ++t) invl[t] = 1.0f / l_st[t];
  for (int f = 0; f < 8; ++f) {
    int d = h * 128 + f * 16 + l16;
    for (int t = 0; t < 4; ++t) {
      int row = b * 2048 + q0 + wave * 16 + quad * 4 + t;
      ctx[(size_t)row * 4096 + d] = f2bf(o_acc[f][t] * invl[t]);
    }
  }
}

// ---------------- launch ----------------
extern "C" void kernel_launch(void* const* d_in, const int* in_sizes, int n_in,
                              void* d_out, int out_size, void* d_ws, size_t ws_size,
                              hipStream_t stream) {
  const float* hs    = (const float*)d_in[0];
  const float* resid = (const float*)d_in[1];
  const float* alibi = (const float*)d_in[2];
  // d_in[3] = attention_mask: deterministic causal, computed analytically
  const float* Wqkv  = (const float*)d_in[4];
  const float* bqkv  = (const float*)d_in[5];
  const float* Wd    = (const float*)d_in[6];
  const float* bd    = (const float*)d_in[7];

  char* ws = (char*)d_ws;
  u16* Abf   = (u16*)(ws);                        // 32 MB
  u16* W1T   = (u16*)(ws + (size_t)33554432);     // 96 MB
  u16* fused = (u16*)(ws + (size_t)134217728);    // 96 MB
  u16* vtb   = (u16*)(ws + (size_t)234881024);    // 32 MB
  u16* ctx   = (u16*)(ws);                        // reuse Abf (dead after GEMM1)
  u16* W2T   = (u16*)(ws + (size_t)33554432);     // reuse W1T (dead after GEMM1)

  cvt_bf16<<<16384, 256, 0, stream>>>(hs, Abf, 16777216);
  cvt_transpose<<<dim3(384, 128), 256, 0, stream>>>(Wqkv, W1T, 4096, 12288);
  // GEMM1: M=4096, N=12288 -> 16 x 48 = 768 tiles (768 % 8 == 0)
  gemm256<0><<<dim3(768), 512, 0, stream>>>(Abf, W1T, bqkv, nullptr, fused, 4096, 12288, 4096);
  transpose_v<<<dim3(32, 64), 256, 0, stream>>>(fused, vtb);
  cvt_transpose<<<dim3(128, 128), 256, 0, stream>>>(Wd, W2T, 4096, 4096);  // after GEMM1 read of W1T
  flash_attn<<<dim3(32, 64), 256, 0, stream>>>(fused, vtb, alibi, ctx);    // ctx overwrites Abf after GEMM1
  // GEMM2: 16 x 16 = 256 tiles (256 % 8 == 0)
  gemm256<1><<<dim3(256), 512, 0, stream>>>(ctx, W2T, bd, resid, d_out, 4096, 4096, 4096);
}